// Round 15
// baseline (1602.012 us; speedup 1.0000x reference)
//
#include <hip/hip_runtime.h>
#include <hip/hip_bf16.h>
#include <stdint.h>

// SAGE (GraphSAGE, LSTM aggregator). f32 I/O, bf16 MFMA internally.
// N=30000, DMAX=16, dims 128 -> 256 -> 64.
// R19 -> R20 (R19: 1083us. FETCH fell 1.705->1.433e6 but dur rose (602->622,
// BW 3.1->2.83): LDS-c round-trips + post-MFMA u-loads killed overlap. Byte
// cuts keep trading against issue rate. R13 (1025us) still best. 7 rounds of
// per-wave-state changes all lose -> try the one untried orthogonal axis:
// BLOCK TOPOLOGY. R13's 16 waves = ONE block; every __syncthreads stalls all
// 16 together, draining the memory pipe once per step (R18 showed mitigating
// this raises BW). Split into 2 co-resident blocks of 512 thr (8 waves):
// same 16 waves/CU, same 128-reg cap, same bytes -- but INDEPENDENT
// barriers: block A drains while block B keeps issuing gathers):
//   1. sage_rec: 512 threads, 8 waves; per wave CPW=F/8 cols (16 or 32),
//      all 64 rows in 2 passes of 2 row-tiles; F=256 adds a 2-half col loop.
//      Named cell regs cA0..cB3 (32 regs F=256). Audit: acc32+c32+u8+ah16+
//      addr~20 ~= 108-116 <= 128; __launch_bounds__(512,4) pins 16 waves/CU.
//      LDS 72.7KB x 2 blocks = 145KB <= 160KB.
//   2. Arithmetic per (row,g,kk) identical to R13 -> bit-same output.
//   FAIL TELLS: WRITE >= 300MB (spill) or occupancy <= 30% (1 blk/CU) ->
//   revert to R13 verbatim.
// Verified layouts (learn_hip m89/m91): A[m=lane&15][k=q*8+j],
// D[row=q*4+r][col=lane&15]; W[4F,F] row-major == gemm-BT B-frag layout.

#define NN 30000
#define DMAXX 16

typedef __bf16 bf16_t;
typedef __bf16 bf16x8 __attribute__((ext_vector_type(8)));
typedef float f32x4 __attribute__((ext_vector_type(4)));
typedef unsigned short u16x4 __attribute__((ext_vector_type(4)));

// persistent scratch (fully rewritten every call; no cross-call state reuse)
__device__ __align__(16) bf16_t g_hbuf[(size_t)NN * 256];    // layer-1 output h1
__device__ __align__(16) bf16_t g_xg1[(size_t)NN * 512];     // feat@Wih1^T + biases
__device__ __align__(16) bf16_t g_xg2[(size_t)NN * 1024];    // h1@Wih2^T + biases
__device__ __align__(16) bf16_t g_wbuf[753664];              // bf16 weight copies
__device__ int g_perm[NN];                                   // degree-sorted node ids

#define OFF_WIH1 0
#define OFF_WHH1 65536
#define OFF_WSELF1 131072
#define OFF_WNEIGH1 163840
#define OFF_WIH2 196608
#define OFF_WHH2 458752
#define OFF_WSELF2 720896
#define OFF_WNEIGH2 737280
#define W_TOTAL 753664

__global__ __launch_bounds__(256)
void cvt_weights(const float* __restrict__ s0, const float* __restrict__ s1,
                 const float* __restrict__ s2, const float* __restrict__ s3,
                 const float* __restrict__ s4, const float* __restrict__ s5,
                 const float* __restrict__ s6, const float* __restrict__ s7)
{
    int i = (blockIdx.x * 256 + threadIdx.x) * 4;
    if (i >= W_TOTAL) return;
    const float* src; int off;
    if      (i < OFF_WHH1)   { src = s0; off = OFF_WIH1; }
    else if (i < OFF_WSELF1) { src = s1; off = OFF_WHH1; }
    else if (i < OFF_WNEIGH1){ src = s2; off = OFF_WSELF1; }
    else if (i < OFF_WIH2)   { src = s3; off = OFF_WNEIGH1; }
    else if (i < OFF_WHH2)   { src = s4; off = OFF_WIH2; }
    else if (i < OFF_WSELF2) { src = s5; off = OFF_WHH2; }
    else if (i < OFF_WNEIGH2){ src = s6; off = OFF_WSELF2; }
    else                     { src = s7; off = OFF_WNEIGH2; }
    float4 v = *reinterpret_cast<const float4*>(src + (i - off));
    bf16_t o[4] __attribute__((aligned(8)));
    o[0] = (bf16_t)v.x; o[1] = (bf16_t)v.y; o[2] = (bf16_t)v.z; o[3] = (bf16_t)v.w;
    *reinterpret_cast<uint2*>(&g_wbuf[i]) = *reinterpret_cast<const uint2*>(o);
}

// counting sort of node ids by DESCENDING degree (LPT block scheduling).
__global__ __launch_bounds__(256)
void build_perm(const int* __restrict__ deg, int* __restrict__ perm)
{
    __shared__ int s_base[DMAXX + 1];
    const int tid = threadIdx.x;
    if (tid <= DMAXX) s_base[tid] = 0;
    __syncthreads();
    for (int i = tid; i < NN; i += 256) {
        int d = deg[i]; d = d < 0 ? 0 : (d > DMAXX ? DMAXX : d);
        atomicAdd(&s_base[d], 1);
    }
    __syncthreads();
    if (tid == 0) {
        int acc = 0;
        for (int d = DMAXX; d >= 0; --d) { int c = s_base[d]; s_base[d] = acc; acc += c; }
    }
    __syncthreads();
    for (int i = tid; i < NN; i += 256) {
        int d = deg[i]; d = d < 0 ? 0 : (d > DMAXX ? DMAXX : d);
        int p = atomicAdd(&s_base[d], 1);
        perm[p] = i;
    }
}

__device__ __forceinline__ float fsig(float x) { return 1.0f / (1.0f + __expf(-x)); }
__device__ __forceinline__ float ftanh(float x) { return 1.0f - 2.0f / (__expf(2.0f * x) + 1.0f); }
__device__ __forceinline__ float bf2f(unsigned short s) {
    union { unsigned u; float f; } v; v.u = ((unsigned)s) << 16; return v.f;
}

// stage a 64-row x-tile (linear rows, row-clamped) into LDS as bf16
template<int F, int LDA, int NT, bool XF32>
__device__ __forceinline__ void stage_tile(bf16_t* dst, const void* src, int row0, int tid)
{
    constexpr int UN = F / 8;          // 16B(bf16) units per row
    for (int e = tid; e < 64 * UN; e += NT) {
        int m = e / UN, sub = e - m * UN;
        int row = row0 + m; if (row >= NN) row = NN - 1;
        if constexpr (XF32) {
            const float* p = (const float*)src + (size_t)row * F + sub * 8;
            float4 f0 = reinterpret_cast<const float4*>(p)[0];
            float4 f1 = reinterpret_cast<const float4*>(p)[1];
            bf16_t t[8] __attribute__((aligned(16)));
            t[0]=(bf16_t)f0.x; t[1]=(bf16_t)f0.y; t[2]=(bf16_t)f0.z; t[3]=(bf16_t)f0.w;
            t[4]=(bf16_t)f1.x; t[5]=(bf16_t)f1.y; t[6]=(bf16_t)f1.z; t[7]=(bf16_t)f1.w;
            *reinterpret_cast<uint4*>(&dst[m * LDA + sub * 8]) = *reinterpret_cast<const uint4*>(t);
        } else {
            const bf16_t* p = (const bf16_t*)src + (size_t)row * F + sub * 8;
            *reinterpret_cast<uint4*>(&dst[m * LDA + sub * 8]) = *reinterpret_cast<const uint4*>(p);
        }
    }
}

// stage a 64-row x-tile with per-row node ids (from LDS array) into LDS
template<int F, int LDA, int NT, bool XF32>
__device__ __forceinline__ void stage_rows(bf16_t* dst, const void* src, const int* nodes, int tid)
{
    constexpr int UN = F / 8;
    for (int e = tid; e < 64 * UN; e += NT) {
        int m = e / UN, sub = e - m * UN;
        int row = nodes[m];
        if constexpr (XF32) {
            const float* p = (const float*)src + (size_t)row * F + sub * 8;
            float4 f0 = reinterpret_cast<const float4*>(p)[0];
            float4 f1 = reinterpret_cast<const float4*>(p)[1];
            bf16_t t[8] __attribute__((aligned(16)));
            t[0]=(bf16_t)f0.x; t[1]=(bf16_t)f0.y; t[2]=(bf16_t)f0.z; t[3]=(bf16_t)f0.w;
            t[4]=(bf16_t)f1.x; t[5]=(bf16_t)f1.y; t[6]=(bf16_t)f1.z; t[7]=(bf16_t)f1.w;
            *reinterpret_cast<uint4*>(&dst[m * LDA + sub * 8]) = *reinterpret_cast<const uint4*>(t);
        } else {
            const bf16_t* p = (const bf16_t*)src + (size_t)row * F + sub * 8;
            *reinterpret_cast<uint4*>(&dst[m * LDA + sub * 8]) = *reinterpret_cast<const uint4*>(p);
        }
    }
}

// xg[N, 4F] (gate-interleaved [c][g]) = x[N,F] @ W[4F,F]^T + b0 + b1
template<int F, int G, int NW, bool XF32>
__global__ __launch_bounds__(NW * 64, 2)
void xg_gemm(const void* __restrict__ xsrc_v, const bf16_t* __restrict__ W,
             const float* __restrict__ b0, const float* __restrict__ b1v,
             bf16_t* __restrict__ xg)
{
    constexpr int LDA = F + 8, KK = F / 32, NT = NW * 64;
    constexpr int CPW = G / NW;        // linear out-cols per wave
    constexpr int CT = CPW / 16;
    static_assert(CPW % 16 == 0 && F % 16 == 0, "");
    const int tid = threadIdx.x, wave = tid >> 6, lane = tid & 63;
    const int q = lane >> 4, m16 = lane & 15;
    const int row0 = blockIdx.x * 64;

    __shared__ __align__(16) bf16_t s_x[64 * LDA];
    stage_tile<F, LDA, NT, XF32>(s_x, xsrc_v, row0, tid);
    __syncthreads();

    #pragma unroll
    for (int ct = 0; ct < CT; ++ct) {
        const int lc0 = wave * CPW + ct * 16;   // linear col block (within one gate)
        const int g = lc0 / F, c0 = lc0 - g * F;
        const float bias = b0[lc0 + m16] + b1v[lc0 + m16];
        f32x4 acc[4];
        #pragma unroll
        for (int rt = 0; rt < 4; ++rt)
            #pragma unroll
            for (int r = 0; r < 4; ++r) acc[rt][r] = bias;
        #pragma unroll
        for (int kk = 0; kk < KK; ++kk) {
            const int ko = kk * 32 + q * 8;
            bf16x8 b = *reinterpret_cast<const bf16x8*>(W + (size_t)(lc0 + m16) * F + ko);
            #pragma unroll
            for (int rt = 0; rt < 4; ++rt) {
                bf16x8 a = *reinterpret_cast<const bf16x8*>(&s_x[(rt * 16 + m16) * LDA + ko]);
                acc[rt] = __builtin_amdgcn_mfma_f32_16x16x32_bf16(a, b, acc[rt], 0, 0, 0);
            }
        }
        #pragma unroll
        for (int rt = 0; rt < 4; ++rt)
            #pragma unroll
            for (int r = 0; r < 4; ++r) {
                int row = row0 + rt * 16 + q * 4 + r;
                if (row < NN)
                    xg[(size_t)row * G + (size_t)(c0 + m16) * 4 + g] = (bf16_t)acc[rt][r];
            }
    }
}

// LSTM recurrence over gathered neighbors + fused fc epilogue.
// Block b: nodes perm[b*64 .. b*64+63] (degree-sorted DESC), loops to
// tmax = max(deg in block). 512 threads = 8 waves; each wave owns CPW=F/8
// cols (16 or 32) and covers all 64 rows in 2 passes of 2 row-tiles;
// F=256 runs the pass-pair twice (two 16-col halves). TWO such blocks
// co-reside per CU (16 waves) with INDEPENDENT barriers.
// gates = gather(xg) + h @ Whh^T ; out = x_self@Wself^T + h_fin@Wneigh^T + b
template<int F, int OUTF, bool RELU, bool XF32, typename OutT>
__global__ __launch_bounds__(512, 4)
void sage_rec(const void* __restrict__ xself_v,
              const bf16_t* __restrict__ xg,
              const int* __restrict__ nbr_idx, const int* __restrict__ deg,
              const int* __restrict__ perm,
              const bf16_t* __restrict__ Whh,
              const bf16_t* __restrict__ Wself, const bf16_t* __restrict__ Wneigh,
              const float* __restrict__ bout, OutT* __restrict__ outp)
{
    constexpr int M = 64, LDA = F + 8, KK = F / 32, NW = 8, NT = 512;
    constexpr int CPW = F / NW;            // cols per wave (16 or 32)
    constexpr int CT2 = CPW / 16;          // 16-col halves per wave (1 or 2)
    constexpr int G4 = 4 * F;
    static_assert(CT2 == 1 || CT2 == 2, "");
    const int tid = threadIdx.x, wave = tid >> 6, lane = tid & 63;
    const int q = lane >> 4, m16 = lane & 15;
    const int colb = wave * CPW + m16;     // half-0 column of this lane
    const int slot0 = blockIdx.x * M;

    __shared__ __align__(16) bf16_t s_h[2][M * LDA];   // double-buffered h
    __shared__ int s_idx[M * DMAXX];
    __shared__ int s_deg[M];
    __shared__ int s_node[M];
    __shared__ int s_tmax;

    for (int i = tid; i < M; i += NT) {
        int slot = slot0 + i; if (slot >= NN) slot = NN - 1;
        int node = perm[slot];
        s_node[i] = node;
        s_deg[i] = deg[node];
    }
    __syncthreads();
    for (int i = tid; i < M * DMAXX; i += NT) {
        int node = s_node[i >> 4];
        int v = nbr_idx[node * DMAXX + (i & 15)];
        if (v < 0) v = 0; if (v >= NN) v = NN - 1;
        s_idx[i] = v;
    }
    for (int i = tid; i < M * LDA; i += NT) s_h[0][i] = (bf16_t)0.0f;
    if (tid == 0) {
        int mx = 1;
        for (int i = 0; i < M; ++i) { int d = s_deg[i]; mx = d > mx ? d : mx; }
        s_tmax = mx;
    }
    __syncthreads();
    const int tmax = s_tmax;   // uniform-degree blocks: ~= block's degree bucket

    // persistent cell state: one f32x4 per (col-half, row-tile); named only
    f32x4 cA0, cA1, cA2, cA3, cB0, cB1, cB2, cB3;
    #pragma unroll
    for (int r = 0; r < 4; ++r) {
        cA0[r]=0.f; cA1[r]=0.f; cA2[r]=0.f; cA3[r]=0.f;
        cB0[r]=0.f; cB1[r]=0.f; cB2[r]=0.f; cB3[r]=0.f;
    }

    // one pass: 2 row-tiles (rtb, rtb+1) x 4 gates for one 16-col group
    auto do_pass = [&](int col, int rtb, f32x4& cX, f32x4& cY,
                       const bf16_t* cur, bf16_t* nxt, int t) {
        // gather gate-init (xg = x@Wih^T + biases), 8B/elem (R13 path)
        u16x4 u[2][4];
        #pragma unroll
        for (int j = 0; j < 2; ++j)
            #pragma unroll
            for (int r = 0; r < 4; ++r) {
                int row = s_idx[((rtb + j) * 16 + q * 4 + r) * DMAXX + t];
                u[j][r] = *reinterpret_cast<const u16x4*>(
                    xg + (size_t)row * G4 + (size_t)col * 4);
            }
        f32x4 acc[2][4];
        #pragma unroll
        for (int j = 0; j < 2; ++j)
            #pragma unroll
            for (int g = 0; g < 4; ++g)
                #pragma unroll
                for (int r = 0; r < 4; ++r) acc[j][g][r] = 0.0f;
        #pragma unroll
        for (int kk = 0; kk < KK; ++kk) {
            const int ko = kk * 32 + q * 8;
            bf16x8 ah0 = *reinterpret_cast<const bf16x8*>(
                &cur[(rtb * 16 + m16) * LDA + ko]);
            bf16x8 ah1 = *reinterpret_cast<const bf16x8*>(
                &cur[((rtb + 1) * 16 + m16) * LDA + ko]);
            #pragma unroll
            for (int g = 0; g < 4; ++g) {
                bf16x8 bh = *reinterpret_cast<const bf16x8*>(
                    Whh + (size_t)(g * F + col) * F + ko);
                acc[0][g] = __builtin_amdgcn_mfma_f32_16x16x32_bf16(ah0, bh, acc[0][g], 0, 0, 0);
                acc[1][g] = __builtin_amdgcn_mfma_f32_16x16x32_bf16(ah1, bh, acc[1][g], 0, 0, 0);
            }
        }
        // pointwise LSTM update + masked store:
        //   t <  deg : write h_new (and update c)
        //   t == deg : copy frozen h from cur (this thread's t-1 write)
        //   t >  deg : skip -- nxt already holds the frozen value
        #pragma unroll
        for (int j = 0; j < 2; ++j) {
            f32x4& cc = j ? cY : cX;
            #pragma unroll
            for (int r = 0; r < 4; ++r) {
                int rowr = (rtb + j) * 16 + q * 4 + r;
                float iv = fsig (acc[j][0][r] + bf2f(u[j][r].x));
                float fv = fsig (acc[j][1][r] + bf2f(u[j][r].y));
                float gv = ftanh(acc[j][2][r] + bf2f(u[j][r].z));
                float ov = fsig (acc[j][3][r] + bf2f(u[j][r].w));
                float cn = fv * cc[r] + iv * gv;
                float hv = ov * ftanh(cn);
                const int pos = rowr * LDA + col;
                int d = s_deg[rowr];
                if (t < d) {
                    cc[r] = cn;
                    nxt[pos] = (bf16_t)hv;
                } else if (t == d) {
                    reinterpret_cast<unsigned short*>(nxt)[pos] =
                        reinterpret_cast<const unsigned short*>(cur)[pos];
                }
            }
        }
    };

    #pragma unroll 1
    for (int t = 0; t < tmax; ++t) {
        const bf16_t* cur = s_h[t & 1];
        bf16_t* nxt = s_h[(t + 1) & 1];
        do_pass(colb, 0, cA0, cA1, cur, nxt, t);
        __builtin_amdgcn_sched_barrier(0);   // keep passes sequential (reg pressure)
        do_pass(colb, 2, cA2, cA3, cur, nxt, t);
        if constexpr (CT2 > 1) {
            __builtin_amdgcn_sched_barrier(0);
            do_pass(colb + 16, 0, cB0, cB1, cur, nxt, t);
            __builtin_amdgcn_sched_barrier(0);
            do_pass(colb + 16, 2, cB2, cB3, cur, nxt, t);
        }
        __syncthreads();   // nxt fully written; cur fully consumed
    }

    // final h is in s_h[tmax&1]; stage self-rows into the other buffer
    const int fb = tmax & 1;
    const bf16_t* hfin = s_h[fb];
    bf16_t* hstage = s_h[fb ^ 1];
    stage_rows<F, LDA, NT, XF32>(hstage, xself_v, s_node, tid);
    __syncthreads();

    // epilogue: out = x_self @ Wself^T + h_fin @ Wneigh^T + bout (+relu)
    constexpr int NCT = OUTF / 16;
    constexpr int TILES = NCT * 4;     // 4 row-tiles of the 64-node tile
    constexpr int TPW = TILES / NW;
    static_assert(TILES % NW == 0, "");
    #pragma unroll
    for (int tt = 0; tt < TPW; ++tt) {
        int tile = wave * TPW + tt;
        int ot = tile % NCT, rt = tile / NCT;
        f32x4 o;
        o[0] = 0.f; o[1] = 0.f; o[2] = 0.f; o[3] = 0.f;
        #pragma unroll
        for (int kk = 0; kk < KK; ++kk) {
            const int ko = kk * 32 + q * 8;
            bf16x8 axs = *reinterpret_cast<const bf16x8*>(&hstage[(rt * 16 + m16) * LDA + ko]);
            bf16x8 am  = *reinterpret_cast<const bf16x8*>(&hfin[(rt * 16 + m16) * LDA + ko]);
            bf16x8 bs = *reinterpret_cast<const bf16x8*>(Wself  + (size_t)(ot * 16 + m16) * F + ko);
            bf16x8 bn = *reinterpret_cast<const bf16x8*>(Wneigh + (size_t)(ot * 16 + m16) * F + ko);
            o = __builtin_amdgcn_mfma_f32_16x16x32_bf16(axs, bs, o, 0, 0, 0);
            o = __builtin_amdgcn_mfma_f32_16x16x32_bf16(am,  bn, o, 0, 0, 0);
        }
        int ocol = ot * 16 + m16;
        float bias = bout[ocol];
        #pragma unroll
        for (int r = 0; r < 4; ++r) {
            int node = s_node[rt * 16 + q * 4 + r];
            float v = o[r] + bias;
            if (RELU) v = fmaxf(v, 0.0f);
            outp[(size_t)node * OUTF + ocol] = (OutT)v;
        }
    }
}

extern "C" void kernel_launch(void* const* d_in, const int* in_sizes, int n_in,
                              void* d_out, int out_size, void* d_ws, size_t ws_size,
                              hipStream_t stream)
{
    const float* feat    = (const float*)d_in[0];
    const int*   nbr     = (const int*)d_in[1];
    const int*   degp    = (const int*)d_in[2];
    const float* Wih1    = (const float*)d_in[3];
    const float* Whh1    = (const float*)d_in[4];
    const float* bih1    = (const float*)d_in[5];
    const float* bhh1    = (const float*)d_in[6];
    const float* Wself1  = (const float*)d_in[7];
    const float* Wneigh1 = (const float*)d_in[8];
    const float* b1      = (const float*)d_in[9];
    const float* Wih2    = (const float*)d_in[10];
    const float* Whh2    = (const float*)d_in[11];
    const float* bih2    = (const float*)d_in[12];
    const float* bhh2    = (const float*)d_in[13];
    const float* Wself2  = (const float*)d_in[14];
    const float* Wneigh2 = (const float*)d_in[15];
    const float* b2      = (const float*)d_in[16];

    bf16_t *hglob, *wglob, *xg1, *xg2;
    int *permg;
    hipGetSymbolAddress((void**)&hglob, HIP_SYMBOL(g_hbuf));
    hipGetSymbolAddress((void**)&wglob, HIP_SYMBOL(g_wbuf));
    hipGetSymbolAddress((void**)&xg1,   HIP_SYMBOL(g_xg1));
    hipGetSymbolAddress((void**)&xg2,   HIP_SYMBOL(g_xg2));
    hipGetSymbolAddress((void**)&permg, HIP_SYMBOL(g_perm));

    cvt_weights<<<W_TOTAL / 4 / 256, 256, 0, stream>>>(
        Wih1, Whh1, Wself1, Wneigh1, Wih2, Whh2, Wself2, Wneigh2);

    build_perm<<<1, 256, 0, stream>>>(degp, permg);

    const int grid = (NN + 63) / 64;   // 469 WGs

    xg_gemm<128, 512, 8, true><<<grid, 512, 0, stream>>>(
        feat, wglob + OFF_WIH1, bih1, bhh1, xg1);

    sage_rec<128, 256, true, true, bf16_t><<<grid, 512, 0, stream>>>(
        feat, xg1, nbr, degp, permg, wglob + OFF_WHH1,
        wglob + OFF_WSELF1, wglob + OFF_WNEIGH1, b1, hglob);

    xg_gemm<256, 1024, 8, false><<<grid, 512, 0, stream>>>(
        hglob, wglob + OFF_WIH2, bih2, bhh2, xg2);

    sage_rec<256, 64, false, false, float><<<grid, 512, 0, stream>>>(
        hglob, xg2, nbr, degp, permg, wglob + OFF_WHH2,
        wglob + OFF_WSELF2, wglob + OFF_WNEIGH2, b2, (float*)d_out);
}

// Round 16
// 1027.563 us; speedup vs baseline: 1.5590x; 1.5590x over previous
//
#include <hip/hip_runtime.h>
#include <hip/hip_bf16.h>
#include <stdint.h>

// SAGE (GraphSAGE, LSTM aggregator). f32 I/O, bf16 MFMA internally.
// N=30000, DMAX=16, dims 128 -> 256 -> 64.
// R20 -> R21 (R20 FAILED both tells: occupancy 27% = blocks did NOT
// co-reside (145KB LDS over the schedulable budget), BW 2.43 TB/s, FETCH up.
// Block-topology axis closed. REVERT to R13 (1025us best; rec2 = FETCH/3.1
// TB/s, pinned by the 128-reg/wave cap at 16 waves/CU -- R14-R20 all lose).
// Remaining safe slack is OUTSIDE rec2: xg_gemm<256> re-reads h1 (15MB),
// re-stages it, and pays a launch, while rec1's epilogue already holds the
// h1 tile):
//   1. FUSE xg2 GEMM into rec1's epilogue: compute the 4 output tiles into
//      regs, barrier, write h1 to global AND stage bf16(h1) into the retired
//      s_h region (64x264 bf16 = 33.8KB <= 34.8KB), barrier, then GEMM
//      h1 @ Wih2^T + bih2+bhh2 -> xg2, same per-output MFMA order and
//      bias-init as xg_gemm<256> -> BIT-IDENTICAL xg2, same layout.
//   2. xg_gemm<256> dispatch deleted. Everything else R13 verbatim.
//   FAIL TELL: total >= 1025us -> revert to pure R13 and declare.
// Verified layouts (learn_hip m89/m91): A[m=lane&15][k=q*8+j],
// D[row=q*4+r][col=lane&15]; W[4F,F] row-major == gemm-BT B-frag layout.

#define NN 30000
#define DMAXX 16

typedef __bf16 bf16_t;
typedef __bf16 bf16x8 __attribute__((ext_vector_type(8)));
typedef float f32x4 __attribute__((ext_vector_type(4)));
typedef unsigned short u16x4 __attribute__((ext_vector_type(4)));

// persistent scratch (fully rewritten every call; no cross-call state reuse)
__device__ __align__(16) bf16_t g_hbuf[(size_t)NN * 256];    // layer-1 output h1
__device__ __align__(16) bf16_t g_xg1[(size_t)NN * 512];     // feat@Wih1^T + biases
__device__ __align__(16) bf16_t g_xg2[(size_t)NN * 1024];    // h1@Wih2^T + biases
__device__ __align__(16) bf16_t g_wbuf[753664];              // bf16 weight copies
__device__ int g_perm[NN];                                   // degree-sorted node ids

#define OFF_WIH1 0
#define OFF_WHH1 65536
#define OFF_WSELF1 131072
#define OFF_WNEIGH1 163840
#define OFF_WIH2 196608
#define OFF_WHH2 458752
#define OFF_WSELF2 720896
#define OFF_WNEIGH2 737280
#define W_TOTAL 753664

__global__ __launch_bounds__(256)
void cvt_weights(const float* __restrict__ s0, const float* __restrict__ s1,
                 const float* __restrict__ s2, const float* __restrict__ s3,
                 const float* __restrict__ s4, const float* __restrict__ s5,
                 const float* __restrict__ s6, const float* __restrict__ s7)
{
    int i = (blockIdx.x * 256 + threadIdx.x) * 4;
    if (i >= W_TOTAL) return;
    const float* src; int off;
    if      (i < OFF_WHH1)   { src = s0; off = OFF_WIH1; }
    else if (i < OFF_WSELF1) { src = s1; off = OFF_WHH1; }
    else if (i < OFF_WNEIGH1){ src = s2; off = OFF_WSELF1; }
    else if (i < OFF_WIH2)   { src = s3; off = OFF_WNEIGH1; }
    else if (i < OFF_WHH2)   { src = s4; off = OFF_WIH2; }
    else if (i < OFF_WSELF2) { src = s5; off = OFF_WHH2; }
    else if (i < OFF_WNEIGH2){ src = s6; off = OFF_WSELF2; }
    else                     { src = s7; off = OFF_WNEIGH2; }
    float4 v = *reinterpret_cast<const float4*>(src + (i - off));
    bf16_t o[4] __attribute__((aligned(8)));
    o[0] = (bf16_t)v.x; o[1] = (bf16_t)v.y; o[2] = (bf16_t)v.z; o[3] = (bf16_t)v.w;
    *reinterpret_cast<uint2*>(&g_wbuf[i]) = *reinterpret_cast<const uint2*>(o);
}

// counting sort of node ids by DESCENDING degree (LPT block scheduling).
__global__ __launch_bounds__(256)
void build_perm(const int* __restrict__ deg, int* __restrict__ perm)
{
    __shared__ int s_base[DMAXX + 1];
    const int tid = threadIdx.x;
    if (tid <= DMAXX) s_base[tid] = 0;
    __syncthreads();
    for (int i = tid; i < NN; i += 256) {
        int d = deg[i]; d = d < 0 ? 0 : (d > DMAXX ? DMAXX : d);
        atomicAdd(&s_base[d], 1);
    }
    __syncthreads();
    if (tid == 0) {
        int acc = 0;
        for (int d = DMAXX; d >= 0; --d) { int c = s_base[d]; s_base[d] = acc; acc += c; }
    }
    __syncthreads();
    for (int i = tid; i < NN; i += 256) {
        int d = deg[i]; d = d < 0 ? 0 : (d > DMAXX ? DMAXX : d);
        int p = atomicAdd(&s_base[d], 1);
        perm[p] = i;
    }
}

__device__ __forceinline__ float fsig(float x) { return 1.0f / (1.0f + __expf(-x)); }
__device__ __forceinline__ float ftanh(float x) { return 1.0f - 2.0f / (__expf(2.0f * x) + 1.0f); }
__device__ __forceinline__ float bf2f(unsigned short s) {
    union { unsigned u; float f; } v; v.u = ((unsigned)s) << 16; return v.f;
}

// stage a 64-row x-tile (linear rows, row-clamped) into LDS as bf16
template<int F, int LDA, int NT, bool XF32>
__device__ __forceinline__ void stage_tile(bf16_t* dst, const void* src, int row0, int tid)
{
    constexpr int UN = F / 8;          // 16B(bf16) units per row
    for (int e = tid; e < 64 * UN; e += NT) {
        int m = e / UN, sub = e - m * UN;
        int row = row0 + m; if (row >= NN) row = NN - 1;
        if constexpr (XF32) {
            const float* p = (const float*)src + (size_t)row * F + sub * 8;
            float4 f0 = reinterpret_cast<const float4*>(p)[0];
            float4 f1 = reinterpret_cast<const float4*>(p)[1];
            bf16_t t[8] __attribute__((aligned(16)));
            t[0]=(bf16_t)f0.x; t[1]=(bf16_t)f0.y; t[2]=(bf16_t)f0.z; t[3]=(bf16_t)f0.w;
            t[4]=(bf16_t)f1.x; t[5]=(bf16_t)f1.y; t[6]=(bf16_t)f1.z; t[7]=(bf16_t)f1.w;
            *reinterpret_cast<uint4*>(&dst[m * LDA + sub * 8]) = *reinterpret_cast<const uint4*>(t);
        } else {
            const bf16_t* p = (const bf16_t*)src + (size_t)row * F + sub * 8;
            *reinterpret_cast<uint4*>(&dst[m * LDA + sub * 8]) = *reinterpret_cast<const uint4*>(p);
        }
    }
}

// stage a 64-row x-tile with per-row node ids (from LDS array) into LDS
template<int F, int LDA, int NT, bool XF32>
__device__ __forceinline__ void stage_rows(bf16_t* dst, const void* src, const int* nodes, int tid)
{
    constexpr int UN = F / 8;
    for (int e = tid; e < 64 * UN; e += NT) {
        int m = e / UN, sub = e - m * UN;
        int row = nodes[m];
        if constexpr (XF32) {
            const float* p = (const float*)src + (size_t)row * F + sub * 8;
            float4 f0 = reinterpret_cast<const float4*>(p)[0];
            float4 f1 = reinterpret_cast<const float4*>(p)[1];
            bf16_t t[8] __attribute__((aligned(16)));
            t[0]=(bf16_t)f0.x; t[1]=(bf16_t)f0.y; t[2]=(bf16_t)f0.z; t[3]=(bf16_t)f0.w;
            t[4]=(bf16_t)f1.x; t[5]=(bf16_t)f1.y; t[6]=(bf16_t)f1.z; t[7]=(bf16_t)f1.w;
            *reinterpret_cast<uint4*>(&dst[m * LDA + sub * 8]) = *reinterpret_cast<const uint4*>(t);
        } else {
            const bf16_t* p = (const bf16_t*)src + (size_t)row * F + sub * 8;
            *reinterpret_cast<uint4*>(&dst[m * LDA + sub * 8]) = *reinterpret_cast<const uint4*>(p);
        }
    }
}

// xg[N, 4F] (gate-interleaved [c][g]) = x[N,F] @ W[4F,F]^T + b0 + b1
template<int F, int G, int NW, bool XF32>
__global__ __launch_bounds__(NW * 64, 2)
void xg_gemm(const void* __restrict__ xsrc_v, const bf16_t* __restrict__ W,
             const float* __restrict__ b0, const float* __restrict__ b1v,
             bf16_t* __restrict__ xg)
{
    constexpr int LDA = F + 8, KK = F / 32, NT = NW * 64;
    constexpr int CPW = G / NW;        // linear out-cols per wave
    constexpr int CT = CPW / 16;
    static_assert(CPW % 16 == 0 && F % 16 == 0, "");
    const int tid = threadIdx.x, wave = tid >> 6, lane = tid & 63;
    const int q = lane >> 4, m16 = lane & 15;
    const int row0 = blockIdx.x * 64;

    __shared__ __align__(16) bf16_t s_x[64 * LDA];
    stage_tile<F, LDA, NT, XF32>(s_x, xsrc_v, row0, tid);
    __syncthreads();

    #pragma unroll
    for (int ct = 0; ct < CT; ++ct) {
        const int lc0 = wave * CPW + ct * 16;   // linear col block (within one gate)
        const int g = lc0 / F, c0 = lc0 - g * F;
        const float bias = b0[lc0 + m16] + b1v[lc0 + m16];
        f32x4 acc[4];
        #pragma unroll
        for (int rt = 0; rt < 4; ++rt)
            #pragma unroll
            for (int r = 0; r < 4; ++r) acc[rt][r] = bias;
        #pragma unroll
        for (int kk = 0; kk < KK; ++kk) {
            const int ko = kk * 32 + q * 8;
            bf16x8 b = *reinterpret_cast<const bf16x8*>(W + (size_t)(lc0 + m16) * F + ko);
            #pragma unroll
            for (int rt = 0; rt < 4; ++rt) {
                bf16x8 a = *reinterpret_cast<const bf16x8*>(&s_x[(rt * 16 + m16) * LDA + ko]);
                acc[rt] = __builtin_amdgcn_mfma_f32_16x16x32_bf16(a, b, acc[rt], 0, 0, 0);
            }
        }
        #pragma unroll
        for (int rt = 0; rt < 4; ++rt)
            #pragma unroll
            for (int r = 0; r < 4; ++r) {
                int row = row0 + rt * 16 + q * 4 + r;
                if (row < NN)
                    xg[(size_t)row * G + (size_t)(c0 + m16) * 4 + g] = (bf16_t)acc[rt][r];
            }
    }
}

// LSTM recurrence over gathered neighbors + fused fc epilogue.
// Block b: nodes perm[b*64 .. b*64+63] (degree-sorted DESC), loops to
// tmax = max(deg in block). 16 waves = NWR row-groups x NWC col-waves.
// Each step runs NPASS sequential passes of 2 row-tiles (spill-free, R13).
// gates = gather(xg) + h @ Whh^T ; out = x_self@Wself^T + h_fin@Wneigh^T + b
// FUSEXG (rec1 only): after the out-epilogue, stage bf16(out) into the
// retired s_h region and compute xg2 = out @ Wih2^T + bih2 + bhh2 in-block
// (bit-identical to the deleted xg_gemm<256> dispatch).
template<int F, int OUTF, bool RELU, bool XF32, typename OutT, bool FUSEXG>
__global__ __launch_bounds__(1024, 4)
void sage_rec(const void* __restrict__ xself_v,
              const bf16_t* __restrict__ xg,
              const int* __restrict__ nbr_idx, const int* __restrict__ deg,
              const int* __restrict__ perm,
              const bf16_t* __restrict__ Whh,
              const bf16_t* __restrict__ Wself, const bf16_t* __restrict__ Wneigh,
              const float* __restrict__ bout, OutT* __restrict__ outp,
              const bf16_t* __restrict__ Wih2, const float* __restrict__ bih2,
              const float* __restrict__ bhh2, bf16_t* __restrict__ xg2out)
{
    constexpr int M = 64, LDA = F + 8, KK = F / 32, NW = 16, NT = 1024;
    constexpr int NWC = F / 16;            // col-waves, 16 cols each
    constexpr int NWR = NW / NWC;          // row-groups (1 for F=256, 2 for F=128)
    constexpr int RT = M / (16 * NWR);     // row-tiles per wave (4 or 2)
    constexpr int NPASS = RT / 2;          // 2 row-tiles per pass
    constexpr int G4 = 4 * F;
    static_assert(NWC * NWR == NW && RT % 2 == 0, "");
    const int tid = threadIdx.x, wave = tid >> 6, lane = tid & 63;
    const int q = lane >> 4, m16 = lane & 15;
    const int wc = wave % NWC, wr = wave / NWC;
    const int ROWB = wr * (RT * 16);       // this wave's row base in tile
    const int col = wc * 16 + m16;         // this lane's output column (per gate)
    const int slot0 = blockIdx.x * M;

    __shared__ __align__(16) bf16_t s_h[2][M * LDA];   // double-buffered h
    __shared__ int s_idx[M * DMAXX];
    __shared__ int s_deg[M];
    __shared__ int s_node[M];
    __shared__ int s_tmax;

    for (int i = tid; i < M; i += NT) {
        int slot = slot0 + i; if (slot >= NN) slot = NN - 1;
        int node = perm[slot];
        s_node[i] = node;
        s_deg[i] = deg[node];
    }
    __syncthreads();
    for (int i = tid; i < M * DMAXX; i += NT) {
        int node = s_node[i >> 4];
        int v = nbr_idx[node * DMAXX + (i & 15)];
        if (v < 0) v = 0; if (v >= NN) v = NN - 1;
        s_idx[i] = v;
    }
    for (int i = tid; i < M * LDA; i += NT) s_h[0][i] = (bf16_t)0.0f;
    if (tid == 0) {
        int mx = 1;
        for (int i = 0; i < M; ++i) { int d = s_deg[i]; mx = d > mx ? d : mx; }
        s_tmax = mx;
    }
    __syncthreads();
    const int tmax = s_tmax;   // uniform-degree blocks: ~= block's degree bucket

    // persistent cell state: one f32x4 per row-tile (named, never runtime-indexed)
    f32x4 c0, c1, c2, c3;
    #pragma unroll
    for (int r = 0; r < 4; ++r) { c0[r]=0.f; c1[r]=0.f; c2[r]=0.f; c3[r]=0.f; }

    // one pass: 2 row-tiles (rtb, rtb+1) x all 4 gates for this wave's 16 cols
    auto do_pass = [&](int rtb, f32x4& cA, f32x4& cB,
                       const bf16_t* cur, bf16_t* nxt, int t) {
        // gather gate-init (xg = x@Wih^T + biases), 8B/elem, 128B/row/wave
        u16x4 u[2][4];
        #pragma unroll
        for (int j = 0; j < 2; ++j)
            #pragma unroll
            for (int r = 0; r < 4; ++r) {
                int row = s_idx[(ROWB + (rtb + j) * 16 + q * 4 + r) * DMAXX + t];
                u[j][r] = *reinterpret_cast<const u16x4*>(
                    xg + (size_t)row * G4 + (size_t)col * 4);
            }
        f32x4 acc[2][4];
        #pragma unroll
        for (int j = 0; j < 2; ++j)
            #pragma unroll
            for (int g = 0; g < 4; ++g)
                #pragma unroll
                for (int r = 0; r < 4; ++r) acc[j][g][r] = 0.0f;
        #pragma unroll
        for (int kk = 0; kk < KK; ++kk) {
            const int ko = kk * 32 + q * 8;
            bf16x8 ah0 = *reinterpret_cast<const bf16x8*>(
                &cur[(ROWB + rtb * 16 + m16) * LDA + ko]);
            bf16x8 ah1 = *reinterpret_cast<const bf16x8*>(
                &cur[(ROWB + (rtb + 1) * 16 + m16) * LDA + ko]);
            #pragma unroll
            for (int g = 0; g < 4; ++g) {
                bf16x8 bh = *reinterpret_cast<const bf16x8*>(
                    Whh + (size_t)(g * F + col) * F + ko);
                acc[0][g] = __builtin_amdgcn_mfma_f32_16x16x32_bf16(ah0, bh, acc[0][g], 0, 0, 0);
                acc[1][g] = __builtin_amdgcn_mfma_f32_16x16x32_bf16(ah1, bh, acc[1][g], 0, 0, 0);
            }
        }
        // pointwise LSTM update + masked store:
        //   t <  deg : write h_new (and update c)
        //   t == deg : copy frozen h from cur (this thread's t-1 write)
        //   t >  deg : skip -- nxt already holds the frozen value
        #pragma unroll
        for (int j = 0; j < 2; ++j) {
            f32x4& cc = j ? cB : cA;
            #pragma unroll
            for (int r = 0; r < 4; ++r) {
                int rowr = ROWB + (rtb + j) * 16 + q * 4 + r;
                float iv = fsig (acc[j][0][r] + bf2f(u[j][r].x));
                float fv = fsig (acc[j][1][r] + bf2f(u[j][r].y));
                float gv = ftanh(acc[j][2][r] + bf2f(u[j][r].z));
                float ov = fsig (acc[j][3][r] + bf2f(u[j][r].w));
                float cn = fv * cc[r] + iv * gv;
                float hv = ov * ftanh(cn);
                const int pos = rowr * LDA + col;
                int d = s_deg[rowr];
                if (t < d) {
                    cc[r] = cn;
                    nxt[pos] = (bf16_t)hv;
                } else if (t == d) {
                    reinterpret_cast<unsigned short*>(nxt)[pos] =
                        reinterpret_cast<const unsigned short*>(cur)[pos];
                }
            }
        }
    };

    #pragma unroll 1
    for (int t = 0; t < tmax; ++t) {
        const bf16_t* cur = s_h[t & 1];
        bf16_t* nxt = s_h[(t + 1) & 1];
        do_pass(0, c0, c1, cur, nxt, t);
        if constexpr (NPASS > 1) {
            __builtin_amdgcn_sched_barrier(0);   // keep passes sequential (reg pressure)
            do_pass(2, c2, c3, cur, nxt, t);
        }
        __syncthreads();   // nxt fully written; cur fully consumed
    }

    // final h is in s_h[tmax&1]; stage self-rows into the other buffer
    const int fb = tmax & 1;
    const bf16_t* hfin = s_h[fb];
    bf16_t* hstage = s_h[fb ^ 1];
    stage_rows<F, LDA, NT, XF32>(hstage, xself_v, s_node, tid);
    __syncthreads();

    // epilogue: out = x_self @ Wself^T + h_fin @ Wneigh^T + bout (+relu)
    constexpr int NCT = OUTF / 16;
    constexpr int TILES = NCT * 4;     // 4 row-tiles of the 64-node tile
    constexpr int TPW = TILES / NW;
    static_assert(TILES % NW == 0, "");

    if constexpr (!FUSEXG) {
        #pragma unroll
        for (int tt = 0; tt < TPW; ++tt) {
            int tile = wave * TPW + tt;
            int ot = tile % NCT, rt = tile / NCT;
            f32x4 o;
            o[0] = 0.f; o[1] = 0.f; o[2] = 0.f; o[3] = 0.f;
            #pragma unroll
            for (int kk = 0; kk < KK; ++kk) {
                const int ko = kk * 32 + q * 8;
                bf16x8 axs = *reinterpret_cast<const bf16x8*>(&hstage[(rt * 16 + m16) * LDA + ko]);
                bf16x8 am  = *reinterpret_cast<const bf16x8*>(&hfin[(rt * 16 + m16) * LDA + ko]);
                bf16x8 bs = *reinterpret_cast<const bf16x8*>(Wself  + (size_t)(ot * 16 + m16) * F + ko);
                bf16x8 bn = *reinterpret_cast<const bf16x8*>(Wneigh + (size_t)(ot * 16 + m16) * F + ko);
                o = __builtin_amdgcn_mfma_f32_16x16x32_bf16(axs, bs, o, 0, 0, 0);
                o = __builtin_amdgcn_mfma_f32_16x16x32_bf16(am,  bn, o, 0, 0, 0);
            }
            int ocol = ot * 16 + m16;
            float bias = bout[ocol];
            #pragma unroll
            for (int r = 0; r < 4; ++r) {
                int node = s_node[rt * 16 + q * 4 + r];
                float v = o[r] + bias;
                if (RELU) v = fmaxf(v, 0.0f);
                outp[(size_t)node * OUTF + ocol] = (OutT)v;
            }
        }
    } else {
        // phase 1: compute all out-tiles into registers (reads hstage/hfin)
        f32x4 ov[TPW];
        #pragma unroll
        for (int tt = 0; tt < TPW; ++tt) {
            int tile = wave * TPW + tt;
            int ot = tile % NCT, rt = tile / NCT;
            f32x4 o;
            o[0] = 0.f; o[1] = 0.f; o[2] = 0.f; o[3] = 0.f;
            #pragma unroll
            for (int kk = 0; kk < KK; ++kk) {
                const int ko = kk * 32 + q * 8;
                bf16x8 axs = *reinterpret_cast<const bf16x8*>(&hstage[(rt * 16 + m16) * LDA + ko]);
                bf16x8 am  = *reinterpret_cast<const bf16x8*>(&hfin[(rt * 16 + m16) * LDA + ko]);
                bf16x8 bs = *reinterpret_cast<const bf16x8*>(Wself  + (size_t)(ot * 16 + m16) * F + ko);
                bf16x8 bn = *reinterpret_cast<const bf16x8*>(Wneigh + (size_t)(ot * 16 + m16) * F + ko);
                o = __builtin_amdgcn_mfma_f32_16x16x32_bf16(axs, bs, o, 0, 0, 0);
                o = __builtin_amdgcn_mfma_f32_16x16x32_bf16(am,  bn, o, 0, 0, 0);
            }
            ov[tt] = o;
        }
        __syncthreads();   // all s_h reads complete; region reusable

        // phase 2: write h1 to global AND stage bf16(h1) into s1 (64 x S1P)
        constexpr int S1P = OUTF + 8;                  // 264: same bank spread as LDA
        static_assert(2 * M * LDA >= M * S1P, "s1 must fit in s_h");
        bf16_t* s1 = &s_h[0][0];
        #pragma unroll
        for (int tt = 0; tt < TPW; ++tt) {
            int tile = wave * TPW + tt;
            int ot = tile % NCT, rt = tile / NCT;
            int ocol = ot * 16 + m16;
            float bias = bout[ocol];
            #pragma unroll
            for (int r = 0; r < 4; ++r) {
                int rowi = rt * 16 + q * 4 + r;
                int node = s_node[rowi];
                float v = ov[tt][r] + bias;
                if (RELU) v = fmaxf(v, 0.0f);
                outp[(size_t)node * OUTF + ocol] = (OutT)v;
                s1[rowi * S1P + ocol] = (bf16_t)v;
            }
        }
        __syncthreads();   // s1 fully written

        // phase 3: xg2 = h1 @ Wih2^T + bih2 + bhh2 (bit-identical to the
        // deleted xg_gemm<256>: same KK order, bias in acc init, same layout)
        constexpr int G2 = 4 * OUTF;                   // 1024
        constexpr int KK2 = OUTF / 32;                 // 8
        constexpr int CPW2 = G2 / NW;                  // 64 linear cols per wave
        constexpr int CT2 = CPW2 / 16;                 // 4
        #pragma unroll
        for (int ct = 0; ct < CT2; ++ct) {
            const int lc0 = wave * CPW2 + ct * 16;     // linear col (within a gate)
            const int g = lc0 / OUTF, cc0 = lc0 - g * OUTF;
            const float bias2 = bih2[lc0 + m16] + bhh2[lc0 + m16];
            f32x4 acc2[4];
            #pragma unroll
            for (int rt = 0; rt < 4; ++rt)
                #pragma unroll
                for (int r = 0; r < 4; ++r) acc2[rt][r] = bias2;
            #pragma unroll
            for (int kk = 0; kk < KK2; ++kk) {
                const int ko = kk * 32 + q * 8;
                bf16x8 b = *reinterpret_cast<const bf16x8*>(
                    Wih2 + (size_t)(lc0 + m16) * OUTF + ko);
                #pragma unroll
                for (int rt = 0; rt < 4; ++rt) {
                    bf16x8 a = *reinterpret_cast<const bf16x8*>(&s1[(rt * 16 + m16) * S1P + ko]);
                    acc2[rt] = __builtin_amdgcn_mfma_f32_16x16x32_bf16(a, b, acc2[rt], 0, 0, 0);
                }
            }
            #pragma unroll
            for (int rt = 0; rt < 4; ++rt)
                #pragma unroll
                for (int r = 0; r < 4; ++r) {
                    int node = s_node[rt * 16 + q * 4 + r];
                    xg2out[(size_t)node * G2 + (size_t)(cc0 + m16) * 4 + g] = (bf16_t)acc2[rt][r];
                }
        }
    }
}

extern "C" void kernel_launch(void* const* d_in, const int* in_sizes, int n_in,
                              void* d_out, int out_size, void* d_ws, size_t ws_size,
                              hipStream_t stream)
{
    const float* feat    = (const float*)d_in[0];
    const int*   nbr     = (const int*)d_in[1];
    const int*   degp    = (const int*)d_in[2];
    const float* Wih1    = (const float*)d_in[3];
    const float* Whh1    = (const float*)d_in[4];
    const float* bih1    = (const float*)d_in[5];
    const float* bhh1    = (const float*)d_in[6];
    const float* Wself1  = (const float*)d_in[7];
    const float* Wneigh1 = (const float*)d_in[8];
    const float* b1      = (const float*)d_in[9];
    const float* Wih2    = (const float*)d_in[10];
    const float* Whh2    = (const float*)d_in[11];
    const float* bih2    = (const float*)d_in[12];
    const float* bhh2    = (const float*)d_in[13];
    const float* Wself2  = (const float*)d_in[14];
    const float* Wneigh2 = (const float*)d_in[15];
    const float* b2      = (const float*)d_in[16];

    bf16_t *hglob, *wglob, *xg1, *xg2;
    int *permg;
    hipGetSymbolAddress((void**)&hglob, HIP_SYMBOL(g_hbuf));
    hipGetSymbolAddress((void**)&wglob, HIP_SYMBOL(g_wbuf));
    hipGetSymbolAddress((void**)&xg1,   HIP_SYMBOL(g_xg1));
    hipGetSymbolAddress((void**)&xg2,   HIP_SYMBOL(g_xg2));
    hipGetSymbolAddress((void**)&permg, HIP_SYMBOL(g_perm));

    cvt_weights<<<W_TOTAL / 4 / 256, 256, 0, stream>>>(
        Wih1, Whh1, Wself1, Wneigh1, Wih2, Whh2, Wself2, Wneigh2);

    build_perm<<<1, 256, 0, stream>>>(degp, permg);

    const int grid = (NN + 63) / 64;   // 469 WGs

    xg_gemm<128, 512, 8, true><<<grid, 512, 0, stream>>>(
        feat, wglob + OFF_WIH1, bih1, bhh1, xg1);

    // rec1: also produces xg2 in its epilogue (xg_gemm<256> deleted)
    sage_rec<128, 256, true, true, bf16_t, true><<<grid, 1024, 0, stream>>>(
        feat, xg1, nbr, degp, permg, wglob + OFF_WHH1,
        wglob + OFF_WSELF1, wglob + OFF_WNEIGH1, b1, hglob,
        wglob + OFF_WIH2, bih2, bhh2, xg2);

    sage_rec<256, 64, false, false, float, false><<<grid, 1024, 0, stream>>>(
        hglob, xg2, nbr, degp, permg, wglob + OFF_WHH2,
        wglob + OFF_WSELF2, wglob + OFF_WNEIGH2, b2, (float*)d_out,
        nullptr, nullptr, nullptr, nullptr);
}